// Round 7
// baseline (227.731 us; speedup 1.0000x reference)
//
#include <hip/hip_runtime.h>

#define NB 4
#define NC 256
#define ND 46
#define NH 55
#define NW 46
#define NN (ND*NH*NW)        // 116380
#define NVEC (NN/4)          // 29095
#define NR 200
#define NL 201
#define NPLANES (NB*NC)      // 1024
#define NFEAT (NB*NR*NC)     // 204800
#define MROI 256             // padded roi rows
#define NCHF 1818            // full 64-voxel chunks: 1818*64 = 116352
#define TAILF4 7             // tail float4s: voxels 116352..116379 (28)
#define ASTEPS 3637          // 32-voxel k-steps (incl. partial last)
#define ASZ ((size_t)ASTEPS * 256 * 32 * 2)   // 59,588,608 B
#define LROW 36              // LDS row stride in u32 (144 B)

typedef __attribute__((ext_vector_type(8))) short bf16x8;
typedef __attribute__((ext_vector_type(4))) float f32x4;

union BU { uint4 u; bf16x8 v; };

// two f32 -> packed bf16 pair (round-half-up, 2 add + 1 v_perm)
__device__ __forceinline__ unsigned pkbf(float x, float y) {
    unsigned ux = __float_as_uint(x) + 0x8000u;
    unsigned uy = __float_as_uint(y) + 0x8000u;
    return __builtin_amdgcn_perm(uy, ux, 0x07060302u);
}

// ---------------- prep: histogram + scatter one-hot A (fragment layout) ----------
// A_sw[(s*256 + roi)*32 + kk] = bf16 1.0 where atlas[32s+kk] == roi+1.
__global__ __launch_bounds__(256) void roi_prep(const int* __restrict__ atlas,
                                                unsigned short* __restrict__ Asw,
                                                float* __restrict__ counts) {
    __shared__ float h[NL];
    const int tid = threadIdx.x;
    for (int i = tid; i < NL; i += 256) h[i] = 0.0f;
    __syncthreads();
    const int v = blockIdx.x * 256 + tid;
    if (v < NN) {
        const int l = atlas[v];
        atomicAdd(&h[l], 1.0f);
        if (l > 0) {
            const int s  = v >> 5;
            const int kk = v & 31;
            Asw[((size_t)s * 256 + (l - 1)) * 32 + kk] = 0x3F80u;
        }
    }
    __syncthreads();
    for (int i = tid; i < NL; i += 256) {
        float c = h[i];
        if (i > 0 && c != 0.0f) atomicAdd(&counts[i - 1], c);
    }
}

// ---------------- main: LDS-staged MFMA GEMM with precomputed A ----------------
// grid = (KCH, NPLANES/64); block = 256 (4 waves).
// Per 64-voxel chunk: coalesced stage fm f32->bf16 into LDS (double-buffered,
// 1 barrier), then 2 k-steps of (4 coalesced A-frag loads + 4 ds_read_b128 +
// 16 MFMA). No per-wave one-hot build, no atlas reads.
__global__ __launch_bounds__(256, 4) void roi_accum_pre(const float* __restrict__ fm,
                                                        const unsigned short* __restrict__ Asw,
                                                        float* __restrict__ partials,
                                                        const int SPl) {
    __shared__ unsigned lds[2][64 * LROW];   // 2 x 9216 B
    const int tid  = threadIdx.x;
    const int wave = tid >> 6;
    const int lane = tid & 63;
    const int g    = lane >> 4;
    const int n    = lane & 15;
    const int pb   = blockIdx.y * 64;
    const int chunk = blockIdx.x;

    const int sr = tid >> 2;      // staging plane
    const int sc = tid & 3;       // staging 16-voxel quarter
    const float4* sf = (const float4*)(fm + (size_t)(pb + sr) * NN);

    const uint4* A4 = (const uint4*)Asw;

    f32x4 acc[4][4];
    #pragma unroll
    for (int t = 0; t < 4; ++t)
        #pragma unroll
        for (int p = 0; p < 4; ++p)
            acc[t][p] = (f32x4){0.f, 0.f, 0.f, 0.f};

    const int t0   = wave * 4;
    const int roiB = t0 * 16 + n;

    const int c0 = chunk * SPl;
    const int c1 = min(c0 + SPl, NCHF);

    float4 L0, L1, L2, L3;
    if (c0 < c1) {
        const float4* p = sf + c0 * 16 + sc * 4;
        L0 = p[0]; L1 = p[1]; L2 = p[2]; L3 = p[3];
    }

    int buf = 0;
    for (int ch = c0; ch < c1; ++ch) {
        const unsigned u0 = pkbf(L0.x, L0.y), u1 = pkbf(L0.z, L0.w);
        const unsigned u2 = pkbf(L1.x, L1.y), u3 = pkbf(L1.z, L1.w);
        const unsigned u4 = pkbf(L2.x, L2.y), u5 = pkbf(L2.z, L2.w);
        const unsigned u6 = pkbf(L3.x, L3.y), u7 = pkbf(L3.z, L3.w);
        unsigned* swp = &lds[buf][sr * LROW + sc * 8];
        ((uint4*)swp)[0] = make_uint4(u0, u1, u2, u3);
        ((uint4*)(swp + 4))[0] = make_uint4(u4, u5, u6, u7);
        __syncthreads();
        if (ch + 1 < c1) {                      // issue next chunk's loads early
            const float4* p = sf + (ch + 1) * 16 + sc * 4;
            L0 = p[0]; L1 = p[1]; L2 = p[2]; L3 = p[3];
        }
        #pragma unroll
        for (int ks = 0; ks < 2; ++ks) {
            const size_t s = (size_t)(ch * 2 + ks);
            const uint4* Ap = A4 + (s * 256 + roiB) * 4 + g;
            BU a0, a1, a2, a3;
            a0.u = Ap[0];
            a1.u = Ap[64];
            a2.u = Ap[128];
            a3.u = Ap[192];
            BU B0, B1, B2, B3;
            B0.u = *(const uint4*)&lds[buf][(0 * 16 + n) * LROW + ks * 16 + g * 4];
            B1.u = *(const uint4*)&lds[buf][(1 * 16 + n) * LROW + ks * 16 + g * 4];
            B2.u = *(const uint4*)&lds[buf][(2 * 16 + n) * LROW + ks * 16 + g * 4];
            B3.u = *(const uint4*)&lds[buf][(3 * 16 + n) * LROW + ks * 16 + g * 4];
            #pragma unroll
            for (int p = 0; p < 4; ++p) {
                const bf16x8 Bv = (p == 0) ? B0.v : (p == 1) ? B1.v : (p == 2) ? B2.v : B3.v;
                acc[0][p] = __builtin_amdgcn_mfma_f32_16x16x32_bf16(a0.v, Bv, acc[0][p], 0, 0, 0);
                acc[1][p] = __builtin_amdgcn_mfma_f32_16x16x32_bf16(a1.v, Bv, acc[1][p], 0, 0, 0);
                acc[2][p] = __builtin_amdgcn_mfma_f32_16x16x32_bf16(a2.v, Bv, acc[2][p], 0, 0, 0);
                acc[3][p] = __builtin_amdgcn_mfma_f32_16x16x32_bf16(a3.v, Bv, acc[3][p], 0, 0, 0);
            }
        }
        buf ^= 1;
    }

    // ---- tail: 28 voxels (k-step 3636), done by the last chunk block ----
    if (chunk == gridDim.x - 1) {
        const float4 zf = {0.f, 0.f, 0.f, 0.f};
        unsigned u[8];
        #pragma unroll
        for (int i = 0; i < 4; ++i) {
            const int idx = sc * 4 + i;
            float4 v = (idx < TAILF4) ? sf[NCHF * 16 + idx] : zf;
            u[2 * i]     = pkbf(v.x, v.y);
            u[2 * i + 1] = pkbf(v.z, v.w);
        }
        unsigned* swp = &lds[buf][sr * LROW + sc * 8];
        ((uint4*)swp)[0] = make_uint4(u[0], u[1], u[2], u[3]);
        ((uint4*)(swp + 4))[0] = make_uint4(u[4], u[5], u[6], u[7]);
        __syncthreads();
        const size_t s = ASTEPS - 1;            // 3636; A rows zero for kk>=28
        const uint4* Ap = A4 + (s * 256 + roiB) * 4 + g;
        BU a0, a1, a2, a3;
        a0.u = Ap[0];
        a1.u = Ap[64];
        a2.u = Ap[128];
        a3.u = Ap[192];
        BU B0, B1, B2, B3;
        B0.u = *(const uint4*)&lds[buf][(0 * 16 + n) * LROW + g * 4];
        B1.u = *(const uint4*)&lds[buf][(1 * 16 + n) * LROW + g * 4];
        B2.u = *(const uint4*)&lds[buf][(2 * 16 + n) * LROW + g * 4];
        B3.u = *(const uint4*)&lds[buf][(3 * 16 + n) * LROW + g * 4];
        #pragma unroll
        for (int p = 0; p < 4; ++p) {
            const bf16x8 Bv = (p == 0) ? B0.v : (p == 1) ? B1.v : (p == 2) ? B2.v : B3.v;
            acc[0][p] = __builtin_amdgcn_mfma_f32_16x16x32_bf16(a0.v, Bv, acc[0][p], 0, 0, 0);
            acc[1][p] = __builtin_amdgcn_mfma_f32_16x16x32_bf16(a1.v, Bv, acc[1][p], 0, 0, 0);
            acc[2][p] = __builtin_amdgcn_mfma_f32_16x16x32_bf16(a2.v, Bv, acc[2][p], 0, 0, 0);
            acc[3][p] = __builtin_amdgcn_mfma_f32_16x16x32_bf16(a3.v, Bv, acc[3][p], 0, 0, 0);
        }
    }

    // store: partials[chunk][roi(256)][plane(1024)]
    // D layout: col = lane&15, row = 4*(lane>>4)+i
    float* pc = partials + (size_t)chunk * (MROI * NPLANES);
    const int rbase = 4 * g;
    #pragma unroll
    for (int t = 0; t < 4; ++t)
        #pragma unroll
        for (int p = 0; p < 4; ++p)
            #pragma unroll
            for (int i = 0; i < 4; ++i)
                pc[(size_t)((t0 + t) * 16 + rbase + i) * NPLANES + (pb + 16 * p + n)] = acc[t][p][i];
}

// ---------------- finalize: reduce chunks + divide + mask ----------------
__global__ __launch_bounds__(256) void roi_final2(const float* __restrict__ partials,
                                                  const float* __restrict__ counts,
                                                  float* __restrict__ out,
                                                  const int kch) {
    const int j = blockIdx.x * 256 + threadIdx.x;
    if (j < NFEAT) {
        const int c = j & (NC - 1);
        const int r = (j >> 8) % NR;
        const int b = j / (NR * NC);
        const int plane = b * NC + c;
        float s = 0.0f;
        for (int ch = 0; ch < kch; ++ch)
            s += partials[((size_t)ch * MROI + r) * NPLANES + plane];
        const float cnt = counts[r];
        out[j] = (cnt > 0.0f) ? s / cnt : 0.0f;
    } else if (j < NFEAT + NB * NR) {
        const int r = (j - NFEAT) % NR;
        out[j] = (counts[r] > 0.0f) ? 1.0f : 0.0f;
    }
}

extern "C" void kernel_launch(void* const* d_in, const int* in_sizes, int n_in,
                              void* d_out, int out_size, void* d_ws, size_t ws_size,
                              hipStream_t stream) {
    const float* fm    = (const float*)d_in[0];
    const int*   atlas = (const int*)d_in[1];
    float*       out   = (float*)d_out;

    float*          counts   = (float*)d_ws;                       // 256 floats
    unsigned short* Asw      = (unsigned short*)(counts + 256);    // ASZ bytes
    float*          partials = (float*)((char*)Asw + ASZ);

    int kch = 64;
    while (kch > 16 &&
           ws_size < 1024 + ASZ + (size_t)kch * MROI * NPLANES * sizeof(float))
        kch >>= 1;
    const int spl = (NCHF + kch - 1) / kch;

    hipMemsetAsync(counts, 0, NR * sizeof(float), stream);
    hipMemsetAsync(Asw, 0, ASZ, stream);

    roi_prep<<<(NN + 255) / 256, 256, 0, stream>>>(atlas, Asw, counts);

    roi_accum_pre<<<dim3(kch, NPLANES / 64), 256, 0, stream>>>(fm, Asw, partials, spl);

    const int total = NFEAT + NB * NR;
    roi_final2<<<(total + 255) / 256, 256, 0, stream>>>(partials, counts, out, kch);
}